// Round 14
// baseline (68.437 us; speedup 1.0000x reference)
//
#include <hip/hip_runtime.h>
#include <cstdint>
#include <cstddef>

#define NB 8
#define NG 64
#define NP 50000
#define NPCH 32                  // argmax p-chunks per row
#define PCH 1563                 // ceil(NP/NPCH); 32*1563 = 50016 >= NP
#define SBLK 98                  // ceil(NP/(128*4)) streaming blocks per batch

__device__ __forceinline__ void opaque(float& x) { asm volatile("" : "+v"(x)); }
__device__ __forceinline__ unsigned long long umax64(unsigned long long a, unsigned long long b) {
    return a > b ? a : b;
}

// ---------------------------------------------------------------------------
// Kernel B: row-oriented argmax partials, recomputing iou from pred (proven R11/R12).
// Grid (NPCH, 8 g-groups, NB); block = 8 g-rows x up-to-PCH preds.
__global__ __launch_bounds__(256) void argmax_part(
    const float* __restrict__ pred,
    const float* __restrict__ gt,
    unsigned long long* __restrict__ part)
{
    __shared__ float s_gx0[8], s_gy0[8], s_gx1[8], s_gy1[8], s_ga[8];
    const int b  = blockIdx.z;
    const int gg = blockIdx.y;
    const int p0 = blockIdx.x * PCH;
    const int tid = threadIdx.x;

    if (tid < 8) {
        const float4 gb = reinterpret_cast<const float4*>(gt)[b * NG + gg * 8 + tid];
        float hw = 0.5f * gb.z, hh = 0.5f * gb.w;   // exact, FMA-safe
        float x0 = gb.x - hw, y0 = gb.y - hh;
        float x1 = gb.x + hw, y1 = gb.y + hh;
        float ga = (x1 - x0) * (y1 - y0);
        opaque(ga);
        s_gx0[tid] = x0; s_gy0[tid] = y0;
        s_gx1[tid] = x1; s_gy1[tid] = y1;
        s_ga[tid]  = ga;
    }
    __syncthreads();

    float        bv[8] = {-1.f,-1.f,-1.f,-1.f,-1.f,-1.f,-1.f,-1.f};
    unsigned int bp[8] = {0,0,0,0,0,0,0,0};

    for (int i = tid; i < PCH; i += 256) {
        const int p = p0 + i;
        if (p >= NP) break;
        const float4 pb = reinterpret_cast<const float4*>(pred)[(size_t)b * NP + p];
        float hw = 0.5f * pb.z, hh = 0.5f * pb.w;
        const float px0 = pb.x - hw, py0 = pb.y - hh;
        const float px1 = pb.x + hw, py1 = pb.y + hh;
        float pa = (px1 - px0) * (py1 - py0);
        opaque(pa);

        #pragma unroll
        for (int j = 0; j < 8; ++j) {
            // identical expression structure to the streaming kernel -> bitwise-equal iou
            float w = fmaxf(fminf(s_gx1[j], px1) - fmaxf(s_gx0[j], px0), 0.0f);
            float h = fmaxf(fminf(s_gy1[j], py1) - fmaxf(s_gy0[j], py0), 0.0f);
            float inter = w * h;
            opaque(inter);                           // numpy op order: (ga+pa)-inter
            float iou = inter / ((s_ga[j] + pa) - inter);  // IEEE div
            if (iou > bv[j]) { bv[j] = iou; bp[j] = (unsigned int)p; }  // static idx
        }
    }

    __shared__ unsigned long long s_part[8][4];
    const int lane = tid & 63;
    const int wv = tid >> 6;
    #pragma unroll
    for (int j = 0; j < 8; ++j) {
        unsigned long long k = 0;
        if (bv[j] >= 0.0f)
            k = ((unsigned long long)__float_as_uint(bv[j]) << 32) |
                (unsigned long long)(0xFFFFFFFFu - bp[j]);
        #pragma unroll
        for (int s = 1; s < 64; s <<= 1)
            k = umax64(k, __shfl_xor(k, s, 64));
        if (lane == 0) s_part[j][wv] = k;
    }
    __syncthreads();

    if (tid < 8) {
        unsigned long long r = umax64(umax64(s_part[tid][0], s_part[tid][1]),
                                      umax64(s_part[tid][2], s_part[tid][3]));
        part[((size_t)b * NG + (size_t)(gg * 8 + tid)) * NPCH + blockIdx.x] = r;
    }
}

// ---------------------------------------------------------------------------
// Kernel S: pure streaming — iou, pos(threshold), neg. 4 preds/thread,
// 128-thread blocks (784 blocks: fine-grained balance), float4 regular stores.
__global__ __launch_bounds__(128) void stream4(
    const float* __restrict__ pred,
    const float* __restrict__ gt,
    float* __restrict__ out_iou,
    float* __restrict__ out_pos,
    float* __restrict__ out_neg)
{
    __shared__ float s_gx0[NG], s_gy0[NG], s_gx1[NG], s_gy1[NG], s_ga[NG];
    const int b = blockIdx.y;
    const int tid = threadIdx.x;

    if (tid < NG) {
        const float4 gb = reinterpret_cast<const float4*>(gt)[b * NG + tid];
        float hw = 0.5f * gb.z, hh = 0.5f * gb.w;   // exact, FMA-safe
        float x0 = gb.x - hw, y0 = gb.y - hh;
        float x1 = gb.x + hw, y1 = gb.y + hh;
        float ga = (x1 - x0) * (y1 - y0);
        opaque(ga);                                  // block FMA contraction
        s_gx0[tid] = x0; s_gy0[tid] = y0;
        s_gx1[tid] = x1; s_gy1[tid] = y1;
        s_ga[tid]  = ga;
    }
    __syncthreads();

    const int p = 4 * (blockIdx.x * 128 + tid);
    if (p >= NP) return;                             // NP%4==0 -> p..p+3 all valid

    float px0[4], py0[4], px1[4], py1[4], pa[4];
    #pragma unroll
    for (int k = 0; k < 4; ++k) {
        const float4 pb = reinterpret_cast<const float4*>(pred)[(size_t)b * NP + p + k];
        float hw = 0.5f * pb.z, hh = 0.5f * pb.w;
        px0[k] = pb.x - hw; py0[k] = pb.y - hh;
        px1[k] = pb.x + hw; py1[k] = pb.y + hh;
        float a = (px1[k] - px0[k]) * (py1[k] - py0[k]);
        opaque(a);
        pa[k] = a;
    }

    float maxv[4] = {0.0f, 0.0f, 0.0f, 0.0f};
    const size_t base = (size_t)b * NG * NP + (size_t)p;

    #pragma unroll 4
    for (int g = 0; g < NG; ++g) {
        const float gx0 = s_gx0[g], gy0 = s_gy0[g];
        const float gx1 = s_gx1[g], gy1 = s_gy1[g];
        const float ga  = s_ga[g];

        float iou[4];
        #pragma unroll
        for (int k = 0; k < 4; ++k) {
            float w = fmaxf(fminf(gx1, px1[k]) - fmaxf(gx0, px0[k]), 0.0f);
            float h = fmaxf(fminf(gy1, py1[k]) - fmaxf(gy0, py0[k]), 0.0f);
            float inter = w * h;
            opaque(inter);                           // numpy op order: (ga+pa)-inter
            iou[k] = inter / ((ga + pa[k]) - inter); // IEEE div
            maxv[k] = fmaxf(maxv[k], iou[k]);
        }

        float4 vi; vi.x = iou[0]; vi.y = iou[1]; vi.z = iou[2]; vi.w = iou[3];
        *reinterpret_cast<float4*>(out_iou + base + (size_t)g * NP) = vi;

        float4 vp;
        vp.x = (iou[0] > 0.7f) ? 1.0f : 0.0f;
        vp.y = (iou[1] > 0.7f) ? 1.0f : 0.0f;
        vp.z = (iou[2] > 0.7f) ? 1.0f : 0.0f;
        vp.w = (iou[3] > 0.7f) ? 1.0f : 0.0f;
        *reinterpret_cast<float4*>(out_pos + base + (size_t)g * NP) = vp;
    }

    float4 vn;
    vn.x = (maxv[0] < 0.3f) ? 1.0f : 0.0f;
    vn.y = (maxv[1] < 0.3f) ? 1.0f : 0.0f;
    vn.z = (maxv[2] < 0.3f) ? 1.0f : 0.0f;
    vn.w = (maxv[3] < 0.3f) ? 1.0f : 0.0f;
    *reinterpret_cast<float4*>(out_neg + (size_t)b * NP + p) = vn;
}

// Reduce each row's NPCH partials, store 1.0 at the argmax position. 512 rows.
__global__ __launch_bounds__(256) void pos_fix(
    const unsigned long long* __restrict__ part,
    float* __restrict__ out_pos)
{
    const int row = blockIdx.x * 256 + threadIdx.x;    // b*NG + g
    if (row >= NB * NG) return;
    const unsigned long long* pr = part + (size_t)row * NPCH;
    unsigned long long r = pr[0];
    #pragma unroll
    for (int c = 1; c < NPCH; ++c) r = umax64(r, pr[c]);
    unsigned int idx = 0xFFFFFFFFu - (unsigned int)(r & 0xFFFFFFFFull);
    if (idx < NP) out_pos[(size_t)row * NP + idx] = 1.0f;
}

// Fallback (ws too small): re-scan the iou matrix for argmax.
__global__ __launch_bounds__(256) void argmax_scan(
    const float* __restrict__ out_iou,
    float* __restrict__ out_pos)
{
    const int row = blockIdx.x;
    const float4* r4 = reinterpret_cast<const float4*>(out_iou + (size_t)row * NP);

    float bv = -1.0f;
    int   bi = 0x7fffffff;
    for (int c = threadIdx.x; c < NP / 4; c += 256) {
        float4 v = r4[c];
        int p = 4 * c;
        if (v.x > bv) { bv = v.x; bi = p; }
        if (v.y > bv) { bv = v.y; bi = p + 1; }
        if (v.z > bv) { bv = v.z; bi = p + 2; }
        if (v.w > bv) { bv = v.w; bi = p + 3; }
    }
    #pragma unroll
    for (int s = 1; s < 64; s <<= 1) {
        float ov = __shfl_xor(bv, s, 64);
        int   oi = __shfl_xor(bi, s, 64);
        if (ov > bv || (ov == bv && oi < bi)) { bv = ov; bi = oi; }
    }
    __shared__ float sv[4];
    __shared__ int   si[4];
    const int wid = threadIdx.x >> 6;
    if ((threadIdx.x & 63) == 0) { sv[wid] = bv; si[wid] = bi; }
    __syncthreads();
    if (threadIdx.x == 0) {
        for (int w = 1; w < 4; ++w)
            if (sv[w] > bv || (sv[w] == bv && si[w] < bi)) { bv = sv[w]; bi = si[w]; }
        out_pos[(size_t)row * NP + bi] = 1.0f;
    }
}

extern "C" void kernel_launch(void* const* d_in, const int* in_sizes, int n_in,
                              void* d_out, int out_size, void* d_ws, size_t ws_size,
                              hipStream_t stream) {
    const float* pred = (const float*)d_in[0];
    const float* gt   = (const float*)d_in[1];
    float* out_iou = (float*)d_out;
    float* out_pos = out_iou + (size_t)NB * NG * NP;
    float* out_neg = out_pos + (size_t)NB * NG * NP;

    const size_t part_bytes = (size_t)NB * NG * NPCH * sizeof(unsigned long long); // 128 KB
    dim3 gridS(SBLK, NB);

    if (ws_size >= part_bytes) {
        unsigned long long* part = (unsigned long long*)d_ws;
        argmax_part<<<dim3(NPCH, NG / 8, NB), dim3(256), 0, stream>>>(pred, gt, part);
        stream4<<<gridS, dim3(128), 0, stream>>>(pred, gt, out_iou, out_pos, out_neg);
        pos_fix<<<dim3((NB * NG + 255) / 256), dim3(256), 0, stream>>>(part, out_pos);
    } else {
        stream4<<<gridS, dim3(128), 0, stream>>>(pred, gt, out_iou, out_pos, out_neg);
        argmax_scan<<<dim3(NB * NG), dim3(256), 0, stream>>>(out_iou, out_pos);
    }
}

// Round 15
// 56.908 us; speedup vs baseline: 1.2026x; 1.2026x over previous
//
#include <hip/hip_runtime.h>
#include <cstdint>
#include <cstddef>

#define NB 8
#define NG 64
#define NP 50000
#define NBLK1 196                // ceil(NP/256) streaming blocks per batch (1 pred/thread)
#define NSTREAM (NBLK1 * NB)     // 1568 streaming blocks
#define NPCH 32                  // argmax p-chunks per row
#define PCH 1563                 // ceil(NP/NPCH); 32*1563 = 50016 >= NP
#define NAMAX (NPCH * (NG / 8) * NB)  // 2048 argmax blocks
#define NTOT (NSTREAM + NAMAX)   // 3616

__device__ __forceinline__ void opaque(float& x) { asm volatile("" : "+v"(x)); }
__device__ __forceinline__ unsigned long long umax64(unsigned long long a, unsigned long long b) {
    return a > b ? a : b;
}

// ---------------------------------------------------------------------------
// Fat kernel, MONOTONIC block-role dispatch (R12-proven): streaming blocks
// dispatch first and saturate the CUs; argmax blocks backfill as streaming
// retires. Streaming role is 1 pred/thread -> 1568 blocks = 6.1/CU = ~24
// waves/CU (R12's 784 was grid-limited at ~12 waves/CU).
template<bool WITH_ARGMAX>
__global__ __launch_bounds__(256) void fused_main(
    const float* __restrict__ pred,
    const float* __restrict__ gt,
    float* __restrict__ out_iou,
    float* __restrict__ out_pos,
    float* __restrict__ out_neg,
    unsigned long long* __restrict__ part)
{
    const int bid = blockIdx.x;
    const int tid = threadIdx.x;

    if (!WITH_ARGMAX || bid < NSTREAM) {
        // ----------------- streaming role: 1 pred/thread -----------------
        __shared__ float s_gx0[NG], s_gy0[NG], s_gx1[NG], s_gy1[NG], s_ga[NG];
        const int b  = bid / NBLK1;
        const int bx = bid % NBLK1;

        if (tid < NG) {
            const float4 gb = reinterpret_cast<const float4*>(gt)[b * NG + tid];
            float hw = 0.5f * gb.z, hh = 0.5f * gb.w;   // exact, FMA-safe
            float x0 = gb.x - hw, y0 = gb.y - hh;
            float x1 = gb.x + hw, y1 = gb.y + hh;
            float ga = (x1 - x0) * (y1 - y0);
            opaque(ga);                                  // block FMA contraction
            s_gx0[tid] = x0; s_gy0[tid] = y0;
            s_gx1[tid] = x1; s_gy1[tid] = y1;
            s_ga[tid]  = ga;
        }
        __syncthreads();

        const int p = bx * 256 + tid;
        if (p >= NP) return;                             // no barriers after this

        const float4 pb = reinterpret_cast<const float4*>(pred)[(size_t)b * NP + p];
        float hw = 0.5f * pb.z, hh = 0.5f * pb.w;
        const float px0 = pb.x - hw, py0 = pb.y - hh;
        const float px1 = pb.x + hw, py1 = pb.y + hh;
        float pa = (px1 - px0) * (py1 - py0);
        opaque(pa);

        float maxv = 0.0f;
        const size_t base = (size_t)b * NG * NP + (size_t)p;

        #pragma unroll 8
        for (int g = 0; g < NG; ++g) {
            const float gx0 = s_gx0[g], gy0 = s_gy0[g];
            const float gx1 = s_gx1[g], gy1 = s_gy1[g];
            const float ga  = s_ga[g];

            float w = fmaxf(fminf(gx1, px1) - fmaxf(gx0, px0), 0.0f);
            float h = fmaxf(fminf(gy1, py1) - fmaxf(gy0, py0), 0.0f);
            float inter = w * h;
            opaque(inter);                               // numpy op order: (ga+pa)-inter
            float iou = inter / ((ga + pa) - inter);     // IEEE div

            out_iou[base + (size_t)g * NP] = iou;
            out_pos[base + (size_t)g * NP] = (iou > 0.7f) ? 1.0f : 0.0f;
            maxv = fmaxf(maxv, iou);
        }

        out_neg[(size_t)b * NP + p] = (maxv < 0.3f) ? 1.0f : 0.0f;
    } else {
        // ----------------- argmax role (f32/u32 accumulators, R12-proven) -----------------
        __shared__ float a_gx0[8], a_gy0[8], a_gx1[8], a_gy1[8], a_ga[8];
        __shared__ unsigned long long s_part[8][4];

        const int a     = bid - NSTREAM;                 // 0..NAMAX-1
        const int chunk = a % NPCH;
        const int t2    = a / NPCH;
        const int gg    = t2 % (NG / 8);
        const int b     = t2 / (NG / 8);
        const int p0    = chunk * PCH;

        if (tid < 8) {
            const float4 gb = reinterpret_cast<const float4*>(gt)[b * NG + gg * 8 + tid];
            float hw = 0.5f * gb.z, hh = 0.5f * gb.w;
            float x0 = gb.x - hw, y0 = gb.y - hh;
            float x1 = gb.x + hw, y1 = gb.y + hh;
            float ga = (x1 - x0) * (y1 - y0);
            opaque(ga);
            a_gx0[tid] = x0; a_gy0[tid] = y0;
            a_gx1[tid] = x1; a_gy1[tid] = y1;
            a_ga[tid]  = ga;
        }
        __syncthreads();

        float        bv[8] = {-1.f,-1.f,-1.f,-1.f,-1.f,-1.f,-1.f,-1.f};
        unsigned int bp[8] = {0,0,0,0,0,0,0,0};

        for (int i = tid; i < PCH; i += 256) {
            const int p = p0 + i;
            if (p >= NP) break;
            const float4 pb = reinterpret_cast<const float4*>(pred)[(size_t)b * NP + p];
            float hw = 0.5f * pb.z, hh = 0.5f * pb.w;
            const float px0 = pb.x - hw, py0 = pb.y - hh;
            const float px1 = pb.x + hw, py1 = pb.y + hh;
            float pa = (px1 - px0) * (py1 - py0);
            opaque(pa);

            #pragma unroll
            for (int j = 0; j < 8; ++j) {
                // identical expression structure to streaming role -> bitwise-equal iou
                float w = fmaxf(fminf(a_gx1[j], px1) - fmaxf(a_gx0[j], px0), 0.0f);
                float h = fmaxf(fminf(a_gy1[j], py1) - fmaxf(a_gy0[j], py0), 0.0f);
                float inter = w * h;
                opaque(inter);                           // numpy op order: (ga+pa)-inter
                float iou = inter / ((a_ga[j] + pa) - inter);  // IEEE div
                if (iou > bv[j]) { bv[j] = iou; bp[j] = (unsigned int)p; }  // static idx
            }
        }

        const int lane = tid & 63;
        const int wv = tid >> 6;
        #pragma unroll
        for (int j = 0; j < 8; ++j) {
            unsigned long long k = 0;
            if (bv[j] >= 0.0f)
                k = ((unsigned long long)__float_as_uint(bv[j]) << 32) |
                    (unsigned long long)(0xFFFFFFFFu - bp[j]);
            #pragma unroll
            for (int s = 1; s < 64; s <<= 1)
                k = umax64(k, __shfl_xor(k, s, 64));
            if (lane == 0) s_part[j][wv] = k;
        }
        __syncthreads();

        if (tid < 8) {
            unsigned long long r = umax64(umax64(s_part[tid][0], s_part[tid][1]),
                                          umax64(s_part[tid][2], s_part[tid][3]));
            part[((size_t)b * NG + (size_t)(gg * 8 + tid)) * NPCH + chunk] = r;
        }
    }
}

// Reduce each row's NPCH partials, store 1.0 at the argmax position. 512 rows.
__global__ __launch_bounds__(256) void pos_fix(
    const unsigned long long* __restrict__ part,
    float* __restrict__ out_pos)
{
    const int row = blockIdx.x * 256 + threadIdx.x;    // b*NG + g
    if (row >= NB * NG) return;
    const unsigned long long* pr = part + (size_t)row * NPCH;
    unsigned long long r = pr[0];
    #pragma unroll
    for (int c = 1; c < NPCH; ++c) r = umax64(r, pr[c]);
    unsigned int idx = 0xFFFFFFFFu - (unsigned int)(r & 0xFFFFFFFFull);
    if (idx < NP) out_pos[(size_t)row * NP + idx] = 1.0f;
}

// Fallback (ws too small): re-scan the iou matrix for argmax.
__global__ __launch_bounds__(256) void argmax_scan(
    const float* __restrict__ out_iou,
    float* __restrict__ out_pos)
{
    const int row = blockIdx.x;
    const float4* r4 = reinterpret_cast<const float4*>(out_iou + (size_t)row * NP);

    float bv = -1.0f;
    int   bi = 0x7fffffff;
    for (int c = threadIdx.x; c < NP / 4; c += 256) {
        float4 v = r4[c];
        int p = 4 * c;
        if (v.x > bv) { bv = v.x; bi = p; }
        if (v.y > bv) { bv = v.y; bi = p + 1; }
        if (v.z > bv) { bv = v.z; bi = p + 2; }
        if (v.w > bv) { bv = v.w; bi = p + 3; }
    }
    #pragma unroll
    for (int s = 1; s < 64; s <<= 1) {
        float ov = __shfl_xor(bv, s, 64);
        int   oi = __shfl_xor(bi, s, 64);
        if (ov > bv || (ov == bv && oi < bi)) { bv = ov; bi = oi; }
    }
    __shared__ float sv[4];
    __shared__ int   si[4];
    const int wid = threadIdx.x >> 6;
    if ((threadIdx.x & 63) == 0) { sv[wid] = bv; si[wid] = bi; }
    __syncthreads();
    if (threadIdx.x == 0) {
        for (int w = 1; w < 4; ++w)
            if (sv[w] > bv || (sv[w] == bv && si[w] < bi)) { bv = sv[w]; bi = si[w]; }
        out_pos[(size_t)row * NP + bi] = 1.0f;
    }
}

extern "C" void kernel_launch(void* const* d_in, const int* in_sizes, int n_in,
                              void* d_out, int out_size, void* d_ws, size_t ws_size,
                              hipStream_t stream) {
    const float* pred = (const float*)d_in[0];
    const float* gt   = (const float*)d_in[1];
    float* out_iou = (float*)d_out;
    float* out_pos = out_iou + (size_t)NB * NG * NP;
    float* out_neg = out_pos + (size_t)NB * NG * NP;

    const size_t part_bytes = (size_t)NB * NG * NPCH * sizeof(unsigned long long); // 128 KB

    if (ws_size >= part_bytes) {
        unsigned long long* part = (unsigned long long*)d_ws;
        fused_main<true><<<dim3(NTOT), dim3(256), 0, stream>>>(
            pred, gt, out_iou, out_pos, out_neg, part);
        pos_fix<<<dim3((NB * NG + 255) / 256), dim3(256), 0, stream>>>(part, out_pos);
    } else {
        fused_main<false><<<dim3(NSTREAM), dim3(256), 0, stream>>>(
            pred, gt, out_iou, out_pos, out_neg, nullptr);
        argmax_scan<<<dim3(NB * NG), dim3(256), 0, stream>>>(out_iou, out_pos);
    }
}